// Round 6
// baseline (2395.032 us; speedup 1.0000x reference)
//
#include <hip/hip_runtime.h>
#include <hip/hip_bf16.h>
#include <math.h>

// Problem constants
#define NSEQ 2048
#define TT   128
#define EE   128
#define HH   256
#define LL   1000
#define NT   512            // 8 waves
#define SEQB 16             // sequences per block (== MFMA N)
#define NBLK (NSEQ / SEQB)  // 128 blocks, fully independent
#define NKT  12             // K-tiles of 32: 4 x + 8 h
#define NMT  64
#define NKT_O 8
#define WSA_ELEMS (NMT * NKT * 64 * 8)      // 768 KB bf16
#define WSO_ELEMS (NMT * NKT_O * 64 * 8)    // 512 KB bf16

typedef __attribute__((ext_vector_type(8))) short bf16x8;
typedef __attribute__((ext_vector_type(4))) float f32x4;

__device__ __forceinline__ unsigned short f2bf(float f) {
    union { float f; unsigned u; } v; v.f = f;
    unsigned r = v.u + 0x7FFF + ((v.u >> 16) & 1);   // RNE
    return (unsigned short)(r >> 16);
}
__device__ __forceinline__ float sigf(float x) { return 1.0f / (1.0f + __expf(-x)); }
__device__ __forceinline__ float tanh_fast(float x) { return 1.0f - 2.0f / (1.0f + __expf(2.0f * x)); }

__global__ void init_out_kernel(float* out) {
    int i = blockIdx.x * blockDim.x + threadIdx.x;
    if (i < HH + 1) out[i] = 0.0f;
}

// Pre-shuffle weights into MFMA A-fragment order, bf16 (layout verified; unchanged).
__global__ void convert_weights(const float* __restrict__ Wih, const float* __restrict__ Whh,
                                const float* __restrict__ Wout,
                                unsigned short* __restrict__ wsA, unsigned short* __restrict__ wsO) {
    int gid = blockIdx.x * blockDim.x + threadIdx.x;
    if (gid < NMT * NKT * 64) {
        int lane = gid & 63, tile = gid >> 6;
        int kt = tile % NKT, mt = tile / NKT;
        int row = mt * 16 + (lane & 15);
        int kb  = kt * 32 + (lane >> 4) * 8;
        unsigned short o[8];
#pragma unroll
        for (int j = 0; j < 8; ++j) {
            int k = kb + j;
            float v = (k < EE) ? Wih[row * EE + k] : Whh[row * HH + (k - EE)];
            o[j] = f2bf(v);
        }
        uint4 pk;
        pk.x = o[0] | ((unsigned)o[1] << 16); pk.y = o[2] | ((unsigned)o[3] << 16);
        pk.z = o[4] | ((unsigned)o[5] << 16); pk.w = o[6] | ((unsigned)o[7] << 16);
        *(uint4*)(wsA + (size_t)gid * 8) = pk;
    } else {
        int g2 = gid - NMT * NKT * 64;
        if (g2 < NMT * NKT_O * 64) {
            int lane = g2 & 63, tile = g2 >> 6;
            int kt = tile % NKT_O, mt = tile / NKT_O;
            int row = mt * 16 + (lane & 15);
            int ub  = kt * 32 + (lane >> 4) * 8;
            unsigned short o[8];
#pragma unroll
            for (int j = 0; j < 8; ++j)
                o[j] = (row < LL) ? f2bf(Wout[row * HH + ub + j]) : (unsigned short)0;
            uint4 pk;
            pk.x = o[0] | ((unsigned)o[1] << 16); pk.y = o[2] | ((unsigned)o[3] << 16);
            pk.z = o[4] | ((unsigned)o[5] << 16); pk.w = o[6] | ((unsigned)o[7] << 16);
            *(uint4*)(wsO + (size_t)g2 * 8) = pk;
        }
    }
}

// Self-sufficient block: 16 seqs, FULL weights in registers (96 KB/wave as
// 384 statically-indexed VGPRs), h-exchange via LDS + one barrier per step.
// Zero inter-block communication -> zero fabric RTTs in the recurrence.
// Wave w owns h-units [32w, 32w+32): gate rows 256g+32w+16jj+4lq+r, jj=mt&1.
__launch_bounds__(NT, 1)
__global__ void lstm_block_kernel(
    const int* __restrict__ tokens, const int* __restrict__ lengths,
    const int* __restrict__ labels, const float* __restrict__ emb,
    const float* __restrict__ bih,  const float* __restrict__ bhh,
    const float* __restrict__ bout,
    const unsigned short* __restrict__ wsA, const unsigned short* __restrict__ wsO,
    float* __restrict__ out)
{
    __shared__ __align__(16) unsigned short xf[2 * 4 * 64 * 8];   // 8 KB x B-frags (dbuf)
    __shared__ __align__(16) unsigned short hB[2 * 8 * 64 * 8];   // 16 KB h B-frags (dbuf)
    __shared__ __align__(16) float bias2[1024];                   // [w][mt][lq][r]
    __shared__ __align__(16) float lg[SEQB * 1024];               // 64 KB logits scratch
    __shared__ int labv[SEQB];

    const int tid = threadIdx.x;
    const int w   = tid >> 6;
    const int l   = tid & 63;
    const int lq  = l >> 4;
    const int ls  = l & 15;           // lane's sequence (0..15)
    const int n0  = blockIdx.x * SEQB;

    const int len_s = lengths[n0 + ls];
    int maxlen = len_s;
#pragma unroll
    for (int s = 1; s < 16; s <<= 1) maxlen = max(maxlen, __shfl_xor(maxlen, s, 64));

    if (tid < SEQB) labv[tid] = labels[n0 + tid];

    // combined bias -> LDS: bias2[w*128 + mt*16 + lq*4 + r]
#pragma unroll
    for (int e = 0; e < 2; ++e) {
        int i2 = 2 * tid + e;
        int r = i2 & 3, lq2 = (i2 >> 2) & 3, mt2 = (i2 >> 4) & 7, w2 = i2 >> 7;
        int row = 256 * (mt2 >> 1) + 32 * w2 + 16 * (mt2 & 1) + 4 * lq2 + r;
        bias2[i2] = bih[row] + bhh[row];
    }
    // zero hB parity 0 (h(0) = 0): 8 KB = 512 threads x uint4
    { uint4 z = {0, 0, 0, 0}; *(uint4*)&hB[(size_t)tid * 8] = z; }

    // ---- full weight slice into registers: 96 frags = 384 VGPRs, static idx ----
    bf16x8 wreg[96];
#pragma unroll
    for (int i = 0; i < 96; ++i) {
        const int mt = i / 12, kt = i - mt * 12;
        const int gmt = 16 * (mt >> 1) + 2 * w + (mt & 1);
        wreg[i] = *(const bf16x8*)(wsA + ((size_t)(gmt * NKT + kt) * 64 + l) * 8);
    }

    // x staging: thread (sq = tid>>5, d0 = 4*(tid&31)) covers seq sq dims d0..d0+3
    const int sq = tid >> 5;
    const int d0 = 4 * (tid & 31);
    const long seqrow = (long)(n0 + sq) * TT;

    auto stageX = [&](const f32x4& xv, int par) {
        const int kt    = d0 >> 5;
        const int lanep = ((d0 >> 3) & 3) * 16 + sq;
        uint2 pk;
        pk.x = f2bf(xv[0]) | ((unsigned)f2bf(xv[1]) << 16);
        pk.y = f2bf(xv[2]) | ((unsigned)f2bf(xv[3]) << 16);
        *(uint2*)&xf[(size_t)((par * 4 + kt) * 64 + lanep) * 8 + (d0 & 4)] = pk;
    };

    // 3-stage x pipeline: token(t+3) -> emb(t+2) -> stage(t+1)
    f32x4 xv; int tokv;
    {
        int t0 = tokens[seqrow + 0];
        f32x4 x0 = *(const f32x4*)(emb + (size_t)t0 * EE + d0);
        stageX(x0, 0);
        int t1 = tokens[seqrow + 1];
        xv   = *(const f32x4*)(emb + (size_t)t1 * EE + d0);
        tokv = tokens[seqrow + 2];
    }

    float c_reg[8];
    uint2 hpk[2];
#pragma unroll
    for (int i = 0; i < 8; ++i) c_reg[i] = 0.0f;
    hpk[0].x = 0; hpk[0].y = 0; hpk[1].x = 0; hpk[1].y = 0;

    __syncthreads();   // bias2 + hB(par0) + xf(par0) + labv visible

    // ---- recurrence: ONE barrier per step, all exchange via LDS ----
    for (int t = 0; t < maxlen; ++t) {
        const int cur = t & 1, nxt = cur ^ 1;

        if (t + 1 < maxlen) stageX(xv, nxt);                         // x(t+1) -> LDS
        f32x4 xnew = *(const f32x4*)(emb + (size_t)tokv * EE + d0);  // x(t+2) gather
        int toknew = tokens[seqrow + min(t + 3, TT - 1)];            // token(t+3)

        // gates = bias + W * [x(t); h(t)]
        f32x4 acc[8];
#pragma unroll
        for (int mt = 0; mt < 8; ++mt)
            acc[mt] = *(const f32x4*)&bias2[(w * 8 + mt) * 16 + lq * 4];
#pragma unroll
        for (int kt = 0; kt < 12; ++kt) {
            const bf16x8 b = (kt < 4)
                ? *(const bf16x8*)&xf[(size_t)((cur * 4 + kt) * 64 + l) * 8]
                : *(const bf16x8*)&hB[(size_t)((cur * 8 + kt - 4) * 64 + l) * 8];
#pragma unroll
            for (int mt = 0; mt < 8; ++mt)
                acc[mt] = __builtin_amdgcn_mfma_f32_16x16x32_bf16(
                    wreg[mt * 12 + kt], b, acc[mt], 0, 0, 0);
        }

        // cell update: lane handles units u = 16jj+4lq+r of seq ls
        const bool live = (t < len_s);
#pragma unroll
        for (int jj = 0; jj < 2; ++jj) {
            if (live) {
                float h[4];
#pragma unroll
                for (int r = 0; r < 4; ++r) {
                    float ig = sigf(acc[0 + jj][r]);
                    float fg = sigf(acc[2 + jj][r]);
                    float gg = tanh_fast(acc[4 + jj][r]);
                    float og = sigf(acc[6 + jj][r]);
                    float cc = fg * c_reg[jj * 4 + r] + ig * gg;
                    c_reg[jj * 4 + r] = cc;
                    h[r] = og * tanh_fast(cc);
                }
                hpk[jj].x = f2bf(h[0]) | ((unsigned)f2bf(h[1]) << 16);
                hpk[jj].y = f2bf(h[2]) | ((unsigned)f2bf(h[3]) << 16);
            }
            // publish h(t+1) in B-frag order (verified mapping)
            const int lanep = (2 * jj + (lq >> 1)) * 16 + ls;
            *(uint2*)&hB[(size_t)((nxt * 8 + w) * 64 + lanep) * 8 + 4 * (lq & 1)] = hpk[jj];
        }

        xv = xnew; tokv = toknew;
        __syncthreads();
    }

    // ---- epilogue 1: embeds = mean(c_f) ----
#pragma unroll
    for (int ci = 0; ci < 8; ++ci) {
        float v = c_reg[ci];
        v += __shfl_xor(v, 1, 64);
        v += __shfl_xor(v, 2, 64);
        v += __shfl_xor(v, 4, 64);
        v += __shfl_xor(v, 8, 64);
        if (ls == 0)
            atomicAdd(&out[32 * w + 16 * (ci >> 2) + 4 * lq + (ci & 3)], v * (1.0f / NSEQ));
    }

    // ---- epilogue 2: logits GEMM + log-softmax for this block's 16 seqs ----
    const int fin = maxlen & 1;
    bf16x8 bq[8];
#pragma unroll
    for (int p = 0; p < 8; ++p)
        bq[p] = *(const bf16x8*)&hB[(size_t)((fin * 8 + p) * 64 + l) * 8];
#pragma unroll
    for (int i = 0; i < 8; ++i) {
        const int mt = 8 * w + i;
        f32x4 a = {0.0f, 0.0f, 0.0f, 0.0f};
#pragma unroll
        for (int p = 0; p < 8; ++p)
            a = __builtin_amdgcn_mfma_f32_16x16x32_bf16(
                *(const bf16x8*)(wsO + ((size_t)(mt * NKT_O + p) * 64 + l) * 8),
                bq[p], a, 0, 0, 0);
#pragma unroll
        for (int r = 0; r < 4; ++r) {
            int cls = 16 * mt + 4 * lq + r;
            lg[(size_t)ls * 1024 + cls] = (cls < LL) ? (a[r] + bout[cls]) : -INFINITY;
        }
    }
    __syncthreads();
    {
        const int s2 = tid >> 5;
        const int i2 = tid & 31;
        const float* row = &lg[(size_t)s2 * 1024];
        float mx = -INFINITY;
#pragma unroll
        for (int k = 0; k < 32; ++k) mx = fmaxf(mx, row[i2 + 32 * k]);
        mx = fmaxf(mx, __shfl_xor(mx, 1, 64));
        mx = fmaxf(mx, __shfl_xor(mx, 2, 64));
        mx = fmaxf(mx, __shfl_xor(mx, 4, 64));
        mx = fmaxf(mx, __shfl_xor(mx, 8, 64));
        mx = fmaxf(mx, __shfl_xor(mx, 16, 64));
        float sm = 0.0f;
#pragma unroll
        for (int k = 0; k < 32; ++k) sm += __expf(row[i2 + 32 * k] - mx);
        sm += __shfl_xor(sm, 1, 64);
        sm += __shfl_xor(sm, 2, 64);
        sm += __shfl_xor(sm, 4, 64);
        sm += __shfl_xor(sm, 8, 64);
        sm += __shfl_xor(sm, 16, 64);
        if (i2 == 0) {
            int lab = labv[s2];
            float lp = row[lab] - mx - __logf(sm);
            atomicAdd(&out[HH], -lp * (1.0f / NSEQ));
        }
    }
}

extern "C" void kernel_launch(void* const* d_in, const int* in_sizes, int n_in,
                              void* d_out, int out_size, void* d_ws, size_t ws_size,
                              hipStream_t stream)
{
    const int*   tokens  = (const int*)d_in[0];
    const int*   lengths = (const int*)d_in[1];
    const int*   labels  = (const int*)d_in[2];
    const float* emb     = (const float*)d_in[3];
    const float* Wih     = (const float*)d_in[4];
    const float* Whh     = (const float*)d_in[5];
    const float* bih     = (const float*)d_in[6];
    const float* bhh     = (const float*)d_in[7];
    const float* Wout    = (const float*)d_in[8];
    const float* bout    = (const float*)d_in[9];
    float* out = (float*)d_out;

    unsigned short* wsA  = (unsigned short*)d_ws;
    unsigned short* wsO  = wsA + WSA_ELEMS;

    hipLaunchKernelGGL(init_out_kernel, dim3(1), dim3(512), 0, stream, out);
    {
        int nthr = NMT * NKT * 64 + NMT * NKT_O * 64;
        hipLaunchKernelGGL(convert_weights, dim3((nthr + 255) / 256), dim3(256), 0, stream,
                           Wih, Whh, Wout, wsA, wsO);
    }
    hipLaunchKernelGGL(lstm_block_kernel, dim3(NBLK), dim3(NT), 0, stream,
                       tokens, lengths, labels, emb, bih, bhh, bout, wsA, wsO, out);
}

// Round 7
// 1107.627 us; speedup vs baseline: 2.1623x; 2.1623x over previous
//
#include <hip/hip_runtime.h>
#include <hip/hip_bf16.h>
#include <math.h>

// Problem constants
#define NSEQ 2048
#define TT   128
#define EE   128
#define HH   256
#define LL   1000
#define NT   512            // 8 waves
#define SEQB 16             // sequences per block (== MFMA N)
#define NBLK (NSEQ / SEQB)  // 128 independent blocks
#define NKT  12             // wsA K-tiles of 32: 4 x + 8 h
#define NMT  64
#define NKT_O 8
#define TCH  16             // t per xg-precompute chunk
#define NTCH (TT / TCH)     // 8 chunks
#define WSA_ELEMS (NMT * NKT * 64 * 8)      // 768 KB bf16
#define WSO_ELEMS (NMT * NKT_O * 64 * 8)    // 512 KB bf16

// xg = x@W_ih^T + b_ih + b_hh for all (n,t), bf16, stored in MFMA C-frag
// order [blk][t][w][mt][lane][4]. 512 MB module .bss (coarse-grained).
__device__ __align__(128) unsigned short g_xg[(size_t)NBLK * TT * 8 * 8 * 64 * 4];

typedef __attribute__((ext_vector_type(8))) short bf16x8;
typedef __attribute__((ext_vector_type(4))) float f32x4;

__device__ __forceinline__ unsigned short f2bf(float f) {
    union { float f; unsigned u; } v; v.f = f;
    unsigned r = v.u + 0x7FFF + ((v.u >> 16) & 1);   // RNE
    return (unsigned short)(r >> 16);
}
__device__ __forceinline__ float sigf(float x) { return 1.0f / (1.0f + __expf(-x)); }
__device__ __forceinline__ float tanh_fast(float x) { return 1.0f - 2.0f / (1.0f + __expf(2.0f * x)); }

__device__ __forceinline__ size_t xg_off(int blk, int t, int w, int mt, int l) {
    return (((((size_t)blk * TT + t) * 8 + w) * 8 + mt) * 64 + l) * 4;
}

__global__ void init_out_kernel(float* out) {
    int i = blockIdx.x * blockDim.x + threadIdx.x;
    if (i < HH + 1) out[i] = 0.0f;
}

// Pre-shuffle weights into MFMA A-fragment order, bf16 (layout verified; unchanged).
__global__ void convert_weights(const float* __restrict__ Wih, const float* __restrict__ Whh,
                                const float* __restrict__ Wout,
                                unsigned short* __restrict__ wsA, unsigned short* __restrict__ wsO) {
    int gid = blockIdx.x * blockDim.x + threadIdx.x;
    if (gid < NMT * NKT * 64) {
        int lane = gid & 63, tile = gid >> 6;
        int kt = tile % NKT, mt = tile / NKT;
        int row = mt * 16 + (lane & 15);
        int kb  = kt * 32 + (lane >> 4) * 8;
        unsigned short o[8];
#pragma unroll
        for (int j = 0; j < 8; ++j) {
            int k = kb + j;
            float v = (k < EE) ? Wih[row * EE + k] : Whh[row * HH + (k - EE)];
            o[j] = f2bf(v);
        }
        uint4 pk;
        pk.x = o[0] | ((unsigned)o[1] << 16); pk.y = o[2] | ((unsigned)o[3] << 16);
        pk.z = o[4] | ((unsigned)o[5] << 16); pk.w = o[6] | ((unsigned)o[7] << 16);
        *(uint4*)(wsA + (size_t)gid * 8) = pk;
    } else {
        int g2 = gid - NMT * NKT * 64;
        if (g2 < NMT * NKT_O * 64) {
            int lane = g2 & 63, tile = g2 >> 6;
            int kt = tile % NKT_O, mt = tile / NKT_O;
            int row = mt * 16 + (lane & 15);
            int ub  = kt * 32 + (lane >> 4) * 8;
            unsigned short o[8];
#pragma unroll
            for (int j = 0; j < 8; ++j)
                o[j] = (row < LL) ? f2bf(Wout[row * HH + ub + j]) : (unsigned short)0;
            uint4 pk;
            pk.x = o[0] | ((unsigned)o[1] << 16); pk.y = o[2] | ((unsigned)o[3] << 16);
            pk.z = o[4] | ((unsigned)o[5] << 16); pk.w = o[6] | ((unsigned)o[7] << 16);
            *(uint4*)(wsO + (size_t)g2 * 8) = pk;
        }
    }
}

// Precompute xg(n,t) = bias + x(n,t) @ W_ih^T for t < len(n).
// Grid: NBLK x NTCH chunks; no sequential dependence; fully parallel.
__launch_bounds__(NT, 2)
__global__ void xg_kernel(const int* __restrict__ tokens, const int* __restrict__ lengths,
                          const float* __restrict__ emb,
                          const float* __restrict__ bih, const float* __restrict__ bhh,
                          const unsigned short* __restrict__ wsA)
{
    __shared__ __align__(16) unsigned short xf[2 * 4 * 64 * 8];   // 8 KB x B-frags (dbuf)
    __shared__ float bias2[1024];

    const int bid = blockIdx.x;
    const int blk = bid & (NBLK - 1);
    const int tch = bid >> 7;
    const int t0c = tch * TCH;
    const int tid = threadIdx.x;
    const int w   = tid >> 6;
    const int l   = tid & 63;
    const int ls  = l & 15;
    const int lq  = l >> 4;
    const int n0  = blk * SEQB;

    const int len_s = lengths[n0 + ls];
    int maxlen = len_s;
#pragma unroll
    for (int s = 1; s < 16; s <<= 1) maxlen = max(maxlen, __shfl_xor(maxlen, s, 64));
    if (t0c >= maxlen) return;
    const int tend = min(t0c + TCH, maxlen);

    // combined bias -> LDS (verified mapping)
#pragma unroll
    for (int e = 0; e < 2; ++e) {
        int i2 = 2 * tid + e;
        int r = i2 & 3, lq2 = (i2 >> 2) & 3, mt2 = (i2 >> 4) & 7, w2 = i2 >> 7;
        int row = 256 * (mt2 >> 1) + 32 * w2 + 16 * (mt2 & 1) + 4 * lq2 + r;
        bias2[i2] = bih[row] + bhh[row];
    }

    // W_ih A-frags (kt 0..3): 32 frags = 128 VGPRs
    bf16x8 wx[32];
#pragma unroll
    for (int mt = 0; mt < 8; ++mt) {
        const int gmt = 16 * (mt >> 1) + 2 * w + (mt & 1);
#pragma unroll
        for (int kt = 0; kt < 4; ++kt)
            wx[mt * 4 + kt] = *(const bf16x8*)(wsA + ((size_t)(gmt * NKT + kt) * 64 + l) * 8);
    }

    // x staging (verified R6 mapping)
    const int sq = tid >> 5;
    const int d0 = 4 * (tid & 31);
    const long seqrow = (long)(n0 + sq) * TT;
    auto stageX = [&](const f32x4& xv, int par) {
        const int kt    = d0 >> 5;
        const int lanep = ((d0 >> 3) & 3) * 16 + sq;
        uint2 pk;
        pk.x = f2bf(xv[0]) | ((unsigned)f2bf(xv[1]) << 16);
        pk.y = f2bf(xv[2]) | ((unsigned)f2bf(xv[3]) << 16);
        *(uint2*)&xf[(size_t)((par * 4 + kt) * 64 + lanep) * 8 + (d0 & 4)] = pk;
    };
    auto gatherX = [&](int t) -> f32x4 {
        int tok = tokens[seqrow + t];
        return *(const f32x4*)(emb + (size_t)tok * EE + d0);
    };

    f32x4 xv = gatherX(t0c);
    __syncthreads();   // bias2 visible

    for (int t = t0c; t < tend; ++t) {
        stageX(xv, t & 1);
        if (t + 1 < tend) xv = gatherX(t + 1);
        __syncthreads();   // staging visible (single barrier per t is safe: dbuf)

        f32x4 acc[8];
#pragma unroll
        for (int mt = 0; mt < 8; ++mt)
            acc[mt] = *(const f32x4*)&bias2[(w * 8 + mt) * 16 + lq * 4];
#pragma unroll
        for (int kt = 0; kt < 4; ++kt) {
            const bf16x8 b = *(const bf16x8*)&xf[(size_t)(((t & 1) * 4 + kt) * 64 + l) * 8];
#pragma unroll
            for (int mt = 0; mt < 8; ++mt)
                acc[mt] = __builtin_amdgcn_mfma_f32_16x16x32_bf16(wx[mt * 4 + kt], b, acc[mt], 0, 0, 0);
        }
        if (t < len_s) {   // lane's C-columns = seq ls
#pragma unroll
            for (int mt = 0; mt < 8; ++mt) {
                uint2 pk;
                pk.x = f2bf(acc[mt][0]) | ((unsigned)f2bf(acc[mt][1]) << 16);
                pk.y = f2bf(acc[mt][2]) | ((unsigned)f2bf(acc[mt][3]) << 16);
                *(uint2*)(g_xg + xg_off(blk, t, w, mt, l)) = pk;
            }
        }
    }
}

// Recurrence: one self-sufficient block per 16 seqs. Only W_hh (512 KB) must
// be resident: 6 K-tiles in regs (192 VGPRs/wave), 2 in LDS (128 KB).
// Gate computation split into jj-halves so only 4 acc tiles live at once
// (each half has all 4 gates for its 16 units -> independent cell update).
// h-exchange: LDS + 1 barrier/step. Zero inter-block traffic.
__launch_bounds__(NT, 2)
__global__ void lstm_main(const int* __restrict__ lengths, const int* __restrict__ labels,
                          const unsigned short* __restrict__ wsA,
                          const unsigned short* __restrict__ wsO,
                          const float* __restrict__ bout, float* __restrict__ out)
{
    __shared__ __align__(16) unsigned short wl[8 * 8 * 2 * 512];  // 128 KB W_hh kt 6,7 (epilogue: logits)
    __shared__ __align__(16) unsigned short hB[2 * 8 * 64 * 8];   // 16 KB h B-frags (dbuf)
    __shared__ int labv[SEQB];

    const int tid = threadIdx.x;
    const int w   = tid >> 6;
    const int l   = tid & 63;
    const int lq  = l >> 4;
    const int ls  = l & 15;
    const int blk = blockIdx.x;
    const int n0  = blk * SEQB;

    const int len_s = lengths[n0 + ls];
    int maxlen = len_s;
#pragma unroll
    for (int s = 1; s < 16; s <<= 1) maxlen = max(maxlen, __shfl_xor(maxlen, s, 64));
    if (tid < SEQB) labv[tid] = labels[n0 + tid];

    // W_hh: regs (orig kt 4..9) + LDS (orig kt 10,11)
    bf16x8 wreg[48];
#pragma unroll
    for (int mt = 0; mt < 8; ++mt) {
        const int gmt = 16 * (mt >> 1) + 2 * w + (mt & 1);
#pragma unroll
        for (int ktR = 0; ktR < 6; ++ktR)
            wreg[mt * 6 + ktR] = *(const bf16x8*)(wsA + ((size_t)(gmt * NKT + 4 + ktR) * 64 + l) * 8);
#pragma unroll
        for (int ktL = 0; ktL < 2; ++ktL)
            *(uint4*)&wl[(size_t)(((w * 8 + mt) * 2 + ktL) * 64 + l) * 8] =
                *(const uint4*)(wsA + ((size_t)(gmt * NKT + 10 + ktL) * 64 + l) * 8);
    }

    // zero hB parity 0 (h(0)=0): 512 threads x 16 B = 8 KB
    { uint4 z = {0, 0, 0, 0}; *(uint4*)&hB[(size_t)tid * 8] = z; }

    // xg prefetch for t=0, both halves
    uint2 pf[2][4];
#pragma unroll
    for (int jj = 0; jj < 2; ++jj)
#pragma unroll
        for (int gg = 0; gg < 4; ++gg)
            pf[jj][gg] = *(const uint2*)(g_xg + xg_off(blk, 0, w, 2 * gg + jj, l));

    float c_reg[8];
    uint2 hpk[2];
#pragma unroll
    for (int i = 0; i < 8; ++i) c_reg[i] = 0.0f;
    hpk[0].x = 0; hpk[0].y = 0; hpk[1].x = 0; hpk[1].y = 0;

    __syncthreads();   // hB(par0) + wl + labv visible

    for (int t = 0; t < maxlen; ++t) {
        const int cur = t & 1, nxt = cur ^ 1;
        const int tn = min(t + 1, TT - 1);
        const bool live = (t < len_s);

#pragma unroll
        for (int jj = 0; jj < 2; ++jj) {
            // acc init from prefetched xg (bf16 -> f32 by shift)
            f32x4 acc[4];
#pragma unroll
            for (int gg = 0; gg < 4; ++gg) {
                acc[gg][0] = __uint_as_float((pf[jj][gg].x & 0xffffu) << 16);
                acc[gg][1] = __uint_as_float(pf[jj][gg].x & 0xffff0000u);
                acc[gg][2] = __uint_as_float((pf[jj][gg].y & 0xffffu) << 16);
                acc[gg][3] = __uint_as_float(pf[jj][gg].y & 0xffff0000u);
            }
            // reissue prefetch for t+1 (full-step latency window)
#pragma unroll
            for (int gg = 0; gg < 4; ++gg)
                pf[jj][gg] = *(const uint2*)(g_xg + xg_off(blk, tn, w, 2 * gg + jj, l));

            // += W_hh * h(t)
#pragma unroll
            for (int kt = 0; kt < 6; ++kt) {
                const bf16x8 b = *(const bf16x8*)&hB[(size_t)((cur * 8 + kt) * 64 + l) * 8];
#pragma unroll
                for (int gg = 0; gg < 4; ++gg)
                    acc[gg] = __builtin_amdgcn_mfma_f32_16x16x32_bf16(
                        wreg[(2 * gg + jj) * 6 + kt], b, acc[gg], 0, 0, 0);
            }
#pragma unroll
            for (int kt = 6; kt < 8; ++kt) {
                const bf16x8 b = *(const bf16x8*)&hB[(size_t)((cur * 8 + kt) * 64 + l) * 8];
#pragma unroll
                for (int gg = 0; gg < 4; ++gg) {
                    const bf16x8 a = *(const bf16x8*)&wl[(size_t)(((w * 8 + (2 * gg + jj)) * 2 + (kt - 6)) * 64 + l) * 8];
                    acc[gg] = __builtin_amdgcn_mfma_f32_16x16x32_bf16(a, b, acc[gg], 0, 0, 0);
                }
            }

            // cell update for units 32w + 16jj + 4lq + r of seq ls
            if (live) {
                float h[4];
#pragma unroll
                for (int r = 0; r < 4; ++r) {
                    float ig = sigf(acc[0][r]);
                    float fg = sigf(acc[1][r]);
                    float gg2 = tanh_fast(acc[2][r]);
                    float og = sigf(acc[3][r]);
                    float cc = fg * c_reg[jj * 4 + r] + ig * gg2;
                    c_reg[jj * 4 + r] = cc;
                    h[r] = og * tanh_fast(cc);
                }
                hpk[jj].x = f2bf(h[0]) | ((unsigned)f2bf(h[1]) << 16);
                hpk[jj].y = f2bf(h[2]) | ((unsigned)f2bf(h[3]) << 16);
            }
            // publish h(t+1) in B-frag order (verified mapping)
            const int lanep = (2 * jj + (lq >> 1)) * 16 + ls;
            *(uint2*)&hB[(size_t)((nxt * 8 + w) * 64 + lanep) * 8 + 4 * (lq & 1)] = hpk[jj];
        }
        __syncthreads();
    }

    // ---- epilogue 1: embeds = mean(c_f) ----
#pragma unroll
    for (int ci = 0; ci < 8; ++ci) {
        float v = c_reg[ci];
        v += __shfl_xor(v, 1, 64);
        v += __shfl_xor(v, 2, 64);
        v += __shfl_xor(v, 4, 64);
        v += __shfl_xor(v, 8, 64);
        if (ls == 0)
            atomicAdd(&out[32 * w + 16 * (ci >> 2) + 4 * lq + (ci & 3)], v * (1.0f / NSEQ));
    }

    // ---- epilogue 2: logits GEMM + log-softmax (lg aliases wl) ----
    const int fin = maxlen & 1;
    float* lg = (float*)wl;            // 16 seqs x 1024 logits = 64 KB
    bf16x8 bq[8];
#pragma unroll
    for (int p = 0; p < 8; ++p)
        bq[p] = *(const bf16x8*)&hB[(size_t)((fin * 8 + p) * 64 + l) * 8];
    __syncthreads();   // all wl (weight) reads done before alias write
#pragma unroll
    for (int i = 0; i < 8; ++i) {
        const int mt = 8 * w + i;
        f32x4 a = {0.0f, 0.0f, 0.0f, 0.0f};
#pragma unroll
        for (int p = 0; p < 8; ++p)
            a = __builtin_amdgcn_mfma_f32_16x16x32_bf16(
                *(const bf16x8*)(wsO + ((size_t)(mt * NKT_O + p) * 64 + l) * 8),
                bq[p], a, 0, 0, 0);
#pragma unroll
        for (int r = 0; r < 4; ++r) {
            int cls = 16 * mt + 4 * lq + r;
            lg[(size_t)ls * 1024 + cls] = (cls < LL) ? (a[r] + bout[cls]) : -INFINITY;
        }
    }
    __syncthreads();
    {
        const int s2 = tid >> 5;
        const int i2 = tid & 31;
        const float* row = &lg[(size_t)s2 * 1024];
        float mx = -INFINITY;
#pragma unroll
        for (int k = 0; k < 32; ++k) mx = fmaxf(mx, row[i2 + 32 * k]);
        mx = fmaxf(mx, __shfl_xor(mx, 1, 64));
        mx = fmaxf(mx, __shfl_xor(mx, 2, 64));
        mx = fmaxf(mx, __shfl_xor(mx, 4, 64));
        mx = fmaxf(mx, __shfl_xor(mx, 8, 64));
        mx = fmaxf(mx, __shfl_xor(mx, 16, 64));
        float sm = 0.0f;
#pragma unroll
        for (int k = 0; k < 32; ++k) sm += __expf(row[i2 + 32 * k] - mx);
        sm += __shfl_xor(sm, 1, 64);
        sm += __shfl_xor(sm, 2, 64);
        sm += __shfl_xor(sm, 4, 64);
        sm += __shfl_xor(sm, 8, 64);
        sm += __shfl_xor(sm, 16, 64);
        if (i2 == 0) {
            int lab = labv[s2];
            float lp = row[lab] - mx - __logf(sm);
            atomicAdd(&out[HH], -lp * (1.0f / NSEQ));
        }
    }
}

extern "C" void kernel_launch(void* const* d_in, const int* in_sizes, int n_in,
                              void* d_out, int out_size, void* d_ws, size_t ws_size,
                              hipStream_t stream)
{
    const int*   tokens  = (const int*)d_in[0];
    const int*   lengths = (const int*)d_in[1];
    const int*   labels  = (const int*)d_in[2];
    const float* emb     = (const float*)d_in[3];
    const float* Wih     = (const float*)d_in[4];
    const float* Whh     = (const float*)d_in[5];
    const float* bih     = (const float*)d_in[6];
    const float* bhh     = (const float*)d_in[7];
    const float* Wout    = (const float*)d_in[8];
    const float* bout    = (const float*)d_in[9];
    float* out = (float*)d_out;

    unsigned short* wsA  = (unsigned short*)d_ws;
    unsigned short* wsO  = wsA + WSA_ELEMS;

    hipLaunchKernelGGL(init_out_kernel, dim3(1), dim3(512), 0, stream, out);
    {
        int nthr = NMT * NKT * 64 + NMT * NKT_O * 64;
        hipLaunchKernelGGL(convert_weights, dim3((nthr + 255) / 256), dim3(256), 0, stream,
                           Wih, Whh, Wout, wsA, wsO);
    }
    hipLaunchKernelGGL(xg_kernel, dim3(NBLK * NTCH), dim3(NT), 0, stream,
                       tokens, lengths, emb, bih, bhh, wsA);
    hipLaunchKernelGGL(lstm_main, dim3(NBLK), dim3(NT), 0, stream,
                       lengths, labels, wsA, wsO, bout, out);
}

// Round 8
// 1040.810 us; speedup vs baseline: 2.3011x; 1.0642x over previous
//
#include <hip/hip_runtime.h>
#include <hip/hip_bf16.h>
#include <math.h>

// Problem constants
#define NSEQ 2048
#define TT   128
#define EE   128
#define HH   256
#define LL   1000
#define NT   512            // 8 waves
#define SEQB 16             // sequences per block (== MFMA N)
#define NBLK (NSEQ / SEQB)  // 128 independent blocks
#define NKT  12             // wsA K-tiles of 32: 4 x + 8 h
#define NMT  64
#define NKT_O 8
#define TCH  16             // t per xg-precompute chunk
#define NTCH (TT / TCH)     // 8 chunks
#define WSA_ELEMS (NMT * NKT * 64 * 8)      // 768 KB bf16
#define WSO_ELEMS (NMT * NKT_O * 64 * 8)    // 512 KB bf16

// xg = x@W_ih^T + b_ih + b_hh for all (n,t), bf16, stored in MFMA C-frag
// order [blk][t][w][mt][lane][4]. 512 MB module .bss (coarse-grained).
__device__ __align__(128) unsigned short g_xg[(size_t)NBLK * TT * 8 * 8 * 64 * 4];

typedef __attribute__((ext_vector_type(8))) short bf16x8;
typedef __attribute__((ext_vector_type(4))) float f32x4;

__device__ __forceinline__ unsigned short f2bf(float f) {
    union { float f; unsigned u; } v; v.f = f;
    unsigned r = v.u + 0x7FFF + ((v.u >> 16) & 1);   // RNE
    return (unsigned short)(r >> 16);
}
__device__ __forceinline__ float sigf(float x) { return 1.0f / (1.0f + __expf(-x)); }
__device__ __forceinline__ float tanh_fast(float x) { return 1.0f - 2.0f / (1.0f + __expf(2.0f * x)); }

__device__ __forceinline__ size_t xg_off(int blk, int t, int w, int mt, int l) {
    return (((((size_t)blk * TT + t) * 8 + w) * 8 + mt) * 64 + l) * 4;
}

__global__ void init_out_kernel(float* out) {
    int i = blockIdx.x * blockDim.x + threadIdx.x;
    if (i < HH + 1) out[i] = 0.0f;
}

// Pre-shuffle weights into MFMA A-fragment order, bf16 (layout verified; unchanged).
__global__ void convert_weights(const float* __restrict__ Wih, const float* __restrict__ Whh,
                                const float* __restrict__ Wout,
                                unsigned short* __restrict__ wsA, unsigned short* __restrict__ wsO) {
    int gid = blockIdx.x * blockDim.x + threadIdx.x;
    if (gid < NMT * NKT * 64) {
        int lane = gid & 63, tile = gid >> 6;
        int kt = tile % NKT, mt = tile / NKT;
        int row = mt * 16 + (lane & 15);
        int kb  = kt * 32 + (lane >> 4) * 8;
        unsigned short o[8];
#pragma unroll
        for (int j = 0; j < 8; ++j) {
            int k = kb + j;
            float v = (k < EE) ? Wih[row * EE + k] : Whh[row * HH + (k - EE)];
            o[j] = f2bf(v);
        }
        uint4 pk;
        pk.x = o[0] | ((unsigned)o[1] << 16); pk.y = o[2] | ((unsigned)o[3] << 16);
        pk.z = o[4] | ((unsigned)o[5] << 16); pk.w = o[6] | ((unsigned)o[7] << 16);
        *(uint4*)(wsA + (size_t)gid * 8) = pk;
    } else {
        int g2 = gid - NMT * NKT * 64;
        if (g2 < NMT * NKT_O * 64) {
            int lane = g2 & 63, tile = g2 >> 6;
            int kt = tile % NKT_O, mt = tile / NKT_O;
            int row = mt * 16 + (lane & 15);
            int ub  = kt * 32 + (lane >> 4) * 8;
            unsigned short o[8];
#pragma unroll
            for (int j = 0; j < 8; ++j)
                o[j] = (row < LL) ? f2bf(Wout[row * HH + ub + j]) : (unsigned short)0;
            uint4 pk;
            pk.x = o[0] | ((unsigned)o[1] << 16); pk.y = o[2] | ((unsigned)o[3] << 16);
            pk.z = o[4] | ((unsigned)o[5] << 16); pk.w = o[6] | ((unsigned)o[7] << 16);
            *(uint4*)(wsO + (size_t)g2 * 8) = pk;
        }
    }
}

// Precompute xg(n,t) = bias + x(n,t) @ W_ih^T for t < len(n).
// waves_per_eu(2,2): allocator may use 256 VGPRs (occupancy capped anyway);
// wx pinned via asm so it cannot be rematerialized from wsA in-loop.
__global__ __launch_bounds__(NT) __attribute__((amdgpu_waves_per_eu(2, 2)))
void xg_kernel(const int* __restrict__ tokens, const int* __restrict__ lengths,
               const float* __restrict__ emb,
               const float* __restrict__ bih, const float* __restrict__ bhh,
               const unsigned short* __restrict__ wsA)
{
    __shared__ __align__(16) unsigned short xf[2 * 4 * 64 * 8];   // 8 KB x B-frags (dbuf)
    __shared__ float bias2[1024];

    const int bid = blockIdx.x;
    const int blk = bid & (NBLK - 1);
    const int tch = bid >> 7;
    const int t0c = tch * TCH;
    const int tid = threadIdx.x;
    const int w   = tid >> 6;
    const int l   = tid & 63;
    const int ls  = l & 15;
    const int lq  = l >> 4;
    const int n0  = blk * SEQB;

    const int len_s = lengths[n0 + ls];
    int maxlen = len_s;
#pragma unroll
    for (int s = 1; s < 16; s <<= 1) maxlen = max(maxlen, __shfl_xor(maxlen, s, 64));
    if (t0c >= maxlen) return;
    const int tend = min(t0c + TCH, maxlen);

    // combined bias -> LDS (verified mapping)
#pragma unroll
    for (int e = 0; e < 2; ++e) {
        int i2 = 2 * tid + e;
        int r = i2 & 3, lq2 = (i2 >> 2) & 3, mt2 = (i2 >> 4) & 7, w2 = i2 >> 7;
        int row = 256 * (mt2 >> 1) + 32 * w2 + 16 * (mt2 & 1) + 4 * lq2 + r;
        bias2[i2] = bih[row] + bhh[row];
    }

    // W_ih A-frags (kt 0..3): 32 frags = 128 VGPRs, pinned
    bf16x8 wx[32];
#pragma unroll
    for (int mt = 0; mt < 8; ++mt) {
        const int gmt = 16 * (mt >> 1) + 2 * w + (mt & 1);
#pragma unroll
        for (int kt = 0; kt < 4; ++kt)
            wx[mt * 4 + kt] = *(const bf16x8*)(wsA + ((size_t)(gmt * NKT + kt) * 64 + l) * 8);
    }
#pragma unroll
    for (int i = 0; i < 32; ++i) asm volatile("" : "+v"(wx[i]));

    // x staging (verified R6 mapping)
    const int sq = tid >> 5;
    const int d0 = 4 * (tid & 31);
    const long seqrow = (long)(n0 + sq) * TT;
    auto stageX = [&](const f32x4& xv, int par) {
        const int kt    = d0 >> 5;
        const int lanep = ((d0 >> 3) & 3) * 16 + sq;
        uint2 pk;
        pk.x = f2bf(xv[0]) | ((unsigned)f2bf(xv[1]) << 16);
        pk.y = f2bf(xv[2]) | ((unsigned)f2bf(xv[3]) << 16);
        *(uint2*)&xf[(size_t)((par * 4 + kt) * 64 + lanep) * 8 + (d0 & 4)] = pk;
    };
    auto gatherX = [&](int t) -> f32x4 {
        int tok = tokens[seqrow + t];
        return *(const f32x4*)(emb + (size_t)tok * EE + d0);
    };

    f32x4 xv = gatherX(t0c);
    __syncthreads();   // bias2 visible

    for (int t = t0c; t < tend; ++t) {
        stageX(xv, t & 1);
        if (t + 1 < tend) xv = gatherX(t + 1);
        __syncthreads();   // staging visible (dbuf -> single barrier per t)

        f32x4 acc[8];
#pragma unroll
        for (int mt = 0; mt < 8; ++mt)
            acc[mt] = *(const f32x4*)&bias2[(w * 8 + mt) * 16 + lq * 4];
#pragma unroll
        for (int kt = 0; kt < 4; ++kt) {
            const bf16x8 b = *(const bf16x8*)&xf[(size_t)(((t & 1) * 4 + kt) * 64 + l) * 8];
#pragma unroll
            for (int mt = 0; mt < 8; ++mt)
                acc[mt] = __builtin_amdgcn_mfma_f32_16x16x32_bf16(wx[mt * 4 + kt], b, acc[mt], 0, 0, 0);
        }
        if (t < len_s) {   // lane's C-columns = seq ls
#pragma unroll
            for (int mt = 0; mt < 8; ++mt) {
                uint2 pk;
                pk.x = f2bf(acc[mt][0]) | ((unsigned)f2bf(acc[mt][1]) << 16);
                pk.y = f2bf(acc[mt][2]) | ((unsigned)f2bf(acc[mt][3]) << 16);
                *(uint2*)(g_xg + xg_off(blk, t, w, mt, l)) = pk;
            }
        }
    }
}

// Recurrence: one self-sufficient block per 16 seqs. W_hh resident on-CU:
// 6 K-tiles in regs (192 VGPRs/wave, PINNED non-rematerializable), 2 in LDS.
// waves_per_eu(2,2) -> 256-VGPR budget. h-exchange: LDS + 1 barrier/step.
__global__ __launch_bounds__(NT) __attribute__((amdgpu_waves_per_eu(2, 2)))
void lstm_main(const int* __restrict__ lengths, const int* __restrict__ labels,
               const unsigned short* __restrict__ wsA,
               const unsigned short* __restrict__ wsO,
               const float* __restrict__ bout, float* __restrict__ out)
{
    __shared__ __align__(16) unsigned short wl[8 * 8 * 2 * 512];  // 128 KB W_hh kt 6,7 (epilogue: logits)
    __shared__ __align__(16) unsigned short hB[2 * 8 * 64 * 8];   // 16 KB h B-frags (dbuf)
    __shared__ int labv[SEQB];

    const int tid = threadIdx.x;
    const int w   = tid >> 6;
    const int l   = tid & 63;
    const int lq  = l >> 4;
    const int ls  = l & 15;
    const int blk = blockIdx.x;
    const int n0  = blk * SEQB;

    const int len_s = lengths[n0 + ls];
    int maxlen = len_s;
#pragma unroll
    for (int s = 1; s < 16; s <<= 1) maxlen = max(maxlen, __shfl_xor(maxlen, s, 64));
    if (tid < SEQB) labv[tid] = labels[n0 + tid];

    // W_hh: regs (orig kt 4..9, pinned) + LDS (orig kt 10,11)
    bf16x8 wreg[48];
#pragma unroll
    for (int mt = 0; mt < 8; ++mt) {
        const int gmt = 16 * (mt >> 1) + 2 * w + (mt & 1);
#pragma unroll
        for (int ktR = 0; ktR < 6; ++ktR)
            wreg[mt * 6 + ktR] = *(const bf16x8*)(wsA + ((size_t)(gmt * NKT + 4 + ktR) * 64 + l) * 8);
#pragma unroll
        for (int ktL = 0; ktL < 2; ++ktL)
            *(uint4*)&wl[(size_t)(((w * 8 + mt) * 2 + ktL) * 64 + l) * 8] =
                *(const uint4*)(wsA + ((size_t)(gmt * NKT + 10 + ktL) * 64 + l) * 8);
    }
#pragma unroll
    for (int i = 0; i < 48; ++i) asm volatile("" : "+v"(wreg[i]));

    // zero hB parity 0 (h(0)=0): 512 threads x 16 B = 8 KB
    { uint4 z = {0, 0, 0, 0}; *(uint4*)&hB[(size_t)tid * 8] = z; }

    // xg prefetch for t=0, both halves
    uint2 pf[2][4];
#pragma unroll
    for (int jj = 0; jj < 2; ++jj)
#pragma unroll
        for (int gg = 0; gg < 4; ++gg)
            pf[jj][gg] = *(const uint2*)(g_xg + xg_off(blk, 0, w, 2 * gg + jj, l));

    float c_reg[8];
    uint2 hpk[2];
#pragma unroll
    for (int i = 0; i < 8; ++i) c_reg[i] = 0.0f;
    hpk[0].x = 0; hpk[0].y = 0; hpk[1].x = 0; hpk[1].y = 0;

    __syncthreads();   // hB(par0) + wl + labv visible

    for (int t = 0; t < maxlen; ++t) {
        const int cur = t & 1, nxt = cur ^ 1;
        const int tn = min(t + 1, TT - 1);
        const bool live = (t < len_s);

#pragma unroll
        for (int jj = 0; jj < 2; ++jj) {
            // acc init from prefetched xg (bf16 -> f32 by shift)
            f32x4 acc[4];
#pragma unroll
            for (int gg = 0; gg < 4; ++gg) {
                acc[gg][0] = __uint_as_float((pf[jj][gg].x & 0xffffu) << 16);
                acc[gg][1] = __uint_as_float(pf[jj][gg].x & 0xffff0000u);
                acc[gg][2] = __uint_as_float((pf[jj][gg].y & 0xffffu) << 16);
                acc[gg][3] = __uint_as_float(pf[jj][gg].y & 0xffff0000u);
            }
            // reissue prefetch for t+1 (full-step latency window)
#pragma unroll
            for (int gg = 0; gg < 4; ++gg)
                pf[jj][gg] = *(const uint2*)(g_xg + xg_off(blk, tn, w, 2 * gg + jj, l));

            // += W_hh * h(t)
#pragma unroll
            for (int kt = 0; kt < 6; ++kt) {
                const bf16x8 b = *(const bf16x8*)&hB[(size_t)((cur * 8 + kt) * 64 + l) * 8];
#pragma unroll
                for (int gg = 0; gg < 4; ++gg)
                    acc[gg] = __builtin_amdgcn_mfma_f32_16x16x32_bf16(
                        wreg[(2 * gg + jj) * 6 + kt], b, acc[gg], 0, 0, 0);
            }
#pragma unroll
            for (int kt = 6; kt < 8; ++kt) {
                const bf16x8 b = *(const bf16x8*)&hB[(size_t)((cur * 8 + kt) * 64 + l) * 8];
#pragma unroll
                for (int gg = 0; gg < 4; ++gg) {
                    const bf16x8 a = *(const bf16x8*)&wl[(size_t)(((w * 8 + (2 * gg + jj)) * 2 + (kt - 6)) * 64 + l) * 8];
                    acc[gg] = __builtin_amdgcn_mfma_f32_16x16x32_bf16(a, b, acc[gg], 0, 0, 0);
                }
            }

            // cell update for units 32w + 16jj + 4lq + r of seq ls
            if (live) {
                float h[4];
#pragma unroll
                for (int r = 0; r < 4; ++r) {
                    float ig = sigf(acc[0][r]);
                    float fg = sigf(acc[1][r]);
                    float gg2 = tanh_fast(acc[2][r]);
                    float og = sigf(acc[3][r]);
                    float cc = fg * c_reg[jj * 4 + r] + ig * gg2;
                    c_reg[jj * 4 + r] = cc;
                    h[r] = og * tanh_fast(cc);
                }
                hpk[jj].x = f2bf(h[0]) | ((unsigned)f2bf(h[1]) << 16);
                hpk[jj].y = f2bf(h[2]) | ((unsigned)f2bf(h[3]) << 16);
            }
            // publish h(t+1) in B-frag order (verified mapping)
            const int lanep = (2 * jj + (lq >> 1)) * 16 + ls;
            *(uint2*)&hB[(size_t)((nxt * 8 + w) * 64 + lanep) * 8 + 4 * (lq & 1)] = hpk[jj];
        }
        __syncthreads();
    }

    // ---- epilogue 1: embeds = mean(c_f) ----
#pragma unroll
    for (int ci = 0; ci < 8; ++ci) {
        float v = c_reg[ci];
        v += __shfl_xor(v, 1, 64);
        v += __shfl_xor(v, 2, 64);
        v += __shfl_xor(v, 4, 64);
        v += __shfl_xor(v, 8, 64);
        if (ls == 0)
            atomicAdd(&out[32 * w + 16 * (ci >> 2) + 4 * lq + (ci & 3)], v * (1.0f / NSEQ));
    }

    // ---- epilogue 2: logits GEMM + log-softmax (lg aliases wl) ----
    const int fin = maxlen & 1;
    float* lg = (float*)wl;            // 16 seqs x 1024 logits = 64 KB
    bf16x8 bq[8];
#pragma unroll
    for (int p = 0; p < 8; ++p)
        bq[p] = *(const bf16x8*)&hB[(size_t)((fin * 8 + p) * 64 + l) * 8];
    __syncthreads();   // all wl (weight) reads done before alias write
#pragma unroll
    for (int i = 0; i < 8; ++i) {
        const int mt = 8 * w + i;
        f32x4 a = {0.0f, 0.0f, 0.0f, 0.0f};
#pragma unroll
        for (int p = 0; p < 8; ++p)
            a = __builtin_amdgcn_mfma_f32_16x16x32_bf16(
                *(const bf16x8*)(wsO + ((size_t)(mt * NKT_O + p) * 64 + l) * 8),
                bq[p], a, 0, 0, 0);
#pragma unroll
        for (int r = 0; r < 4; ++r) {
            int cls = 16 * mt + 4 * lq + r;
            lg[(size_t)ls * 1024 + cls] = (cls < LL) ? (a[r] + bout[cls]) : -INFINITY;
        }
    }
    __syncthreads();
    {
        const int s2 = tid >> 5;
        const int i2 = tid & 31;
        const float* row = &lg[(size_t)s2 * 1024];
        float mx = -INFINITY;
#pragma unroll
        for (int k = 0; k < 32; ++k) mx = fmaxf(mx, row[i2 + 32 * k]);
        mx = fmaxf(mx, __shfl_xor(mx, 1, 64));
        mx = fmaxf(mx, __shfl_xor(mx, 2, 64));
        mx = fmaxf(mx, __shfl_xor(mx, 4, 64));
        mx = fmaxf(mx, __shfl_xor(mx, 8, 64));
        mx = fmaxf(mx, __shfl_xor(mx, 16, 64));
        float sm = 0.0f;
#pragma unroll
        for (int k = 0; k < 32; ++k) sm += __expf(row[i2 + 32 * k] - mx);
        sm += __shfl_xor(sm, 1, 64);
        sm += __shfl_xor(sm, 2, 64);
        sm += __shfl_xor(sm, 4, 64);
        sm += __shfl_xor(sm, 8, 64);
        sm += __shfl_xor(sm, 16, 64);
        if (i2 == 0) {
            int lab = labv[s2];
            float lp = row[lab] - mx - __logf(sm);
            atomicAdd(&out[HH], -lp * (1.0f / NSEQ));
        }
    }
}

extern "C" void kernel_launch(void* const* d_in, const int* in_sizes, int n_in,
                              void* d_out, int out_size, void* d_ws, size_t ws_size,
                              hipStream_t stream)
{
    const int*   tokens  = (const int*)d_in[0];
    const int*   lengths = (const int*)d_in[1];
    const int*   labels  = (const int*)d_in[2];
    const float* emb     = (const float*)d_in[3];
    const float* Wih     = (const float*)d_in[4];
    const float* Whh     = (const float*)d_in[5];
    const float* bih     = (const float*)d_in[6];
    const float* bhh     = (const float*)d_in[7];
    const float* Wout    = (const float*)d_in[8];
    const float* bout    = (const float*)d_in[9];
    float* out = (float*)d_out;

    unsigned short* wsA  = (unsigned short*)d_ws;
    unsigned short* wsO  = wsA + WSA_ELEMS;

    hipLaunchKernelGGL(init_out_kernel, dim3(1), dim3(512), 0, stream, out);
    {
        int nthr = NMT * NKT * 64 + NMT * NKT_O * 64;
        hipLaunchKernelGGL(convert_weights, dim3((nthr + 255) / 256), dim3(256), 0, stream,
                           Wih, Whh, Wout, wsA, wsO);
    }
    hipLaunchKernelGGL(xg_kernel, dim3(NBLK * NTCH), dim3(NT), 0, stream,
                       tokens, lengths, emb, bih, bhh, wsA);
    hipLaunchKernelGGL(lstm_main, dim3(NBLK), dim3(NT), 0, stream,
                       lengths, labels, wsA, wsO, bout, out);
}